// Round 12
// baseline (490.321 us; speedup 1.0000x reference)
//
#include <hip/hip_runtime.h>
#include <hip/hip_bf16.h>

// Mamba2 vision model, MI355X. 64x128-tile bf16 MFMA GEMMs; in_proj/conv2 use
// BDIR=1 (B-frags read DIRECT from L2-resident weight, no Bs LDS staging --
// mechanism validated in scan3go's out_proj). conv1 computes im2col inline
// (IMC arm) and writes conv2's patch layout. Split scan kernels; scan1 uses
// the 256x512 all-heads shape; k_scan3go fuses final scan + gating/RMS +
// out_proj GEMM + residual/LN (r10). Shapes: B=8, L=1024, D_MODEL=256,
// D_INNER=512, NHEADS=8, HEADDIM=64, D_STATE=16, CONV_DIM=544,
// D_IN_PROJ=1064, N_LAYERS=4.

#define DEV __device__ __forceinline__
typedef __hip_bfloat16 bf16;
typedef unsigned short ushort_t;
typedef __attribute__((ext_vector_type(8))) short s8v;
typedef __attribute__((ext_vector_type(8))) unsigned short u8v;
typedef __attribute__((ext_vector_type(4))) unsigned short u4v;
typedef __attribute__((ext_vector_type(4))) float f4v;

#define CHUNK 32
#define NCH 32
#define YST 520   // y_s / C_lds row stride (bf16 units / +4-bank rotation)

// small-param fp32 scratch offsets
#define SP_CONVW 0
#define SP_CONVB 8704
#define SP_DTB   10880
#define SP_ALOG  10912
#define SP_DSK   10944
#define SP_RMSW  10976
#define SP_LNG   13024
#define SP_LNB   14048
#define SP_HLG   15072
#define SP_HLB   15328
#define SP_HW    15584
#define SP_HB    18144
#define SP_G1    18160
#define SP_B1    18288
#define SP_G2    18416
#define SP_B2    18672
#define SP_TOTAL 18928

DEV float bf2f(bf16 h) { return __bfloat162float(h); }
DEV bf16 f2bf(float f) { return __float2bfloat16(f); }
DEV float us2f(ushort_t u) { return __uint_as_float(((unsigned int)u) << 16); }
DEV ushort_t f2bfs(float f) {
    unsigned int u = __float_as_uint(f);
    return (ushort_t)((u + 0x7FFFu + ((u >> 16) & 1u)) >> 16);
}
DEV float ldf(const void* p, size_t i, int bf) {
    return bf ? us2f(((const ushort_t*)p)[i]) : ((const float*)p)[i];
}
DEV ushort_t ldbf(const void* p, size_t i, int bf) {
    return bf ? ((const ushort_t*)p)[i] : f2bfs(((const float*)p)[i]);
}
DEV int mode_of(const void* g1) { return (((const unsigned int*)g1)[0] == 0x3F800000u) ? 0 : 1; }
DEV float sigmoidf_(float x) { return 1.f / (1.f + __expf(-x)); }
DEV float geluf_(float x) { return 0.5f * x * (1.f + erff(x * 0.70710678118654752f)); }

// ---------------- merged: small params -> fp32 scratch + weight transpose ----------------
__global__ void k_prep(const void* cw, const void* cb, const void* dtb, const void* alog,
                       const void* dsk, const void* rmsw, const void* lng, const void* lnb,
                       const void* hlg, const void* hlb, const void* hw, const void* hb,
                       const void* g1, const void* b1, const void* g2, const void* b2,
                       const void* w1, const void* w2, const void* inw, const void* outw,
                       float* __restrict__ sp, ushort_t* __restrict__ wT) {
    int md = mode_of(g1);
    int i = blockIdx.x * 256 + threadIdx.x;
    if (i < SP_TOTAL) {
        float v;
        if (i < SP_CONVB) v = ldf(cw, i, md);
        else if (i < SP_DTB) v = ldf(cb, i - SP_CONVB, md);
        else if (i < SP_ALOG) v = ldf(dtb, i - SP_DTB, md);
        else if (i < SP_DSK) v = ldf(alog, i - SP_ALOG, md);
        else if (i < SP_RMSW) v = ldf(dsk, i - SP_DSK, md);
        else if (i < SP_LNG) v = ldf(rmsw, i - SP_RMSW, md);
        else if (i < SP_LNB) v = ldf(lng, i - SP_LNG, md);
        else if (i < SP_HLG) v = ldf(lnb, i - SP_LNB, md);
        else if (i < SP_HLB) v = ldf(hlg, i - SP_HLG, md);
        else if (i < SP_HW) v = ldf(hlb, i - SP_HLB, md);
        else if (i < SP_HB) v = ldf(hw, i - SP_HW, md);
        else if (i < SP_G1) v = (i - SP_HB < 10) ? ldf(hb, i - SP_HB, md) : 0.f;
        else if (i < SP_B1) v = ldf(g1, i - SP_G1, md);
        else if (i < SP_G2) v = ldf(b1, i - SP_B1, md);
        else if (i < SP_B2) v = ldf(g2, i - SP_G2, md);
        else v = ldf(b2, i - SP_B2, md);
        sp[i] = v;
        return;
    }
    int iw = i - SP_TOTAL;
    if (iw >= 2142208) return;
    ushort_t v;
    if (iw < 4096) {
        int oc = iw >> 5, k = iw & 31;
        v = (k < 27) ? ldbf(w1, (size_t)oc * 27 + k, md) : 0;
    } else if (iw < 528384) {
        int j = iw - 4096;
        int oc = j >> 11, k = j & 2047;
        int c = k & 127, kykx = k >> 7;
        v = ldbf(w2, (size_t)(oc * 128 + c) * 16 + kykx, md);
    } else if (iw < 1617920) {
        int j = iw - 528384;
        int l = j / 272384, r = j % 272384;
        int n = r >> 8, k = r & 255;
        v = ldbf(inw, (size_t)l * 272384 + (size_t)k * 1064 + n, md);
    } else {
        int j = iw - 1617920;
        int l = j >> 17, r = j & 131071;
        int n = r >> 9, k = r & 511;
        v = ldbf(outw, (size_t)l * 131072 + (size_t)k * 256 + n, md);
    }
    wT[iw] = v;
}

// ---------------- bf16 MFMA GEMM, 64x128 tile, dbuf LDS A, split-K capable ----------------
// A: bf16 [m][k] stride K (IMC=1: conv1 im2col inline from xsrc).
// Wt: bf16 [n][k] stride K. BDIR=1: B-frags direct from global (L2), no Bs LDS.
// EPI 0: plain write (CBF picks bf16/fp32; fp32 -> C + z*M*N split-K).
// EPI 1: gelu(g[n]*v+b[n]) bf16. EPI 2: BN+GELU + conv2-patch-layout write.
template <int EPI, int CBF, int BK, int IMC, int BDIR>
__global__ __launch_bounds__(256, 3) void k_gemmT(const ushort_t* __restrict__ A,
                                                  const ushort_t* __restrict__ Wt, void* __restrict__ C,
                                                  int M, int N, int K, int klen,
                                                  const float* __restrict__ g, const float* __restrict__ bb,
                                                  const void* __restrict__ xsrc,
                                                  const void* __restrict__ g1p) {
    constexpr int KG = BK / 8;
    constexpr int EA = BK / 4;
    constexpr int EB = BK / 2;
    constexpr int AU = EA / 8;
    constexpr int BU = EB / 8;
    constexpr int BSZ = BDIR ? 8 : 2 * 128 * BK;
    __shared__ __align__(16) ushort_t As[2][64 * BK];
    __shared__ __align__(16) ushort_t Bs[BSZ];
    int tid = threadIdx.x;
    int m0 = blockIdx.y * 64, n0 = blockIdx.x * 128;
    int koff = blockIdx.z * klen;
    int w = tid >> 6, lane = tid & 63;
    int wm = (w >> 1) * 32, wn = (w & 1) * 64;
    int lm = lane & 15, quad = lane >> 4;
    int ar = tid >> 2, ak = (tid & 3) * EA;
    int br = tid >> 1, bk = (tid & 1) * EB;
    bool bvalid = (n0 + br) < N;
    int md = 0;
    if constexpr (IMC) md = mode_of(g1p);

    u8v pa[AU], pb[BU];
    auto loadT = [&](int kb) {
        if constexpr (IMC) {
            int m = m0 + ar;
            int xx2 = m & 127, yy2 = (m >> 7) & 127, bb2 = m >> 14;
            u8v v = (u8v)0;
#pragma unroll
            for (int j = 0; j < 8; j++) {
                int k = ak + j;
                if (k < 27) {
                    int ci = k / 9, r2 = k - ci * 9;
                    int dy = r2 / 3, dx = r2 - dy * 3;
                    int sy = yy2 + dy - 1, sx = xx2 + dx - 1;
                    if (sy >= 0 && sy < 128 && sx >= 0 && sx < 128) {
                        size_t idx = ((size_t)(bb2 * 3 + ci) * 128 + sy) * 128 + sx;
                        v[j] = md ? ((const ushort_t*)xsrc)[idx] : f2bfs(((const float*)xsrc)[idx]);
                    }
                }
            }
            pa[0] = v;
        } else {
            const u8v* ap = (const u8v*)(A + (size_t)(m0 + ar) * K + koff + kb + ak);
#pragma unroll
            for (int j = 0; j < AU; j++) pa[j] = ap[j];
        }
        if constexpr (!BDIR) {
            if (bvalid) {
                const u8v* bp = (const u8v*)(Wt + (size_t)(n0 + br) * K + koff + kb + bk);
#pragma unroll
                for (int j = 0; j < BU; j++) pb[j] = bp[j];
            } else {
#pragma unroll
                for (int j = 0; j < BU; j++) pb[j] = (u8v)0;
            }
        }
    };
    auto storeT = [&](int buf) {
        int ag = ak >> 3;
#pragma unroll
        for (int j = 0; j < AU; j++)
            *(u8v*)&As[buf][((ar >> 4) * KG + ag + j) * 128 + (ar & 15) * 8] = pa[j];
        if constexpr (!BDIR) {
            int bg = bk >> 3;
#pragma unroll
            for (int j = 0; j < BU; j++)
                *(u8v*)&Bs[(size_t)buf * 128 * BK + ((br >> 4) * KG + bg + j) * 128 + (br & 15) * 8] = pb[j];
        }
    };

    f4v acc[2][4];
#pragma unroll
    for (int i = 0; i < 2; i++)
#pragma unroll
        for (int j = 0; j < 4; j++) acc[i][j] = (f4v){0.f, 0.f, 0.f, 0.f};

    int niter = klen / BK;
    loadT(0);
    storeT(0);
    if (niter > 1) loadT(BK);
    __syncthreads();
    for (int it = 0; it < niter; it++) {
        int buf = it & 1;
        if (it + 1 < niter) {
            storeT(buf ^ 1);
            if (it + 2 < niter) loadT((it + 2) * BK);
        }
        s8v bd[2][4];
        if constexpr (BDIR) {
            // prefetch this K-step's B-frags straight from global (L2-resident weight)
#pragma unroll
            for (int kk = 0; kk < BK / 32; kk++)
#pragma unroll
                for (int j = 0; j < 4; j++)
                    bd[kk][j] = *(const s8v*)(Wt + (size_t)(n0 + wn + j * 16 + lm) * K + koff +
                                              it * BK + kk * 32 + quad * 8);
        }
#pragma unroll
        for (int kk = 0; kk < BK / 32; kk++) {
            s8v af[2], bfr[4];
#pragma unroll
            for (int i = 0; i < 2; i++)
                af[i] = *(const s8v*)&As[buf][(((wm >> 4) + i) * KG + kk * 4 + quad) * 128 + lm * 8];
#pragma unroll
            for (int j = 0; j < 4; j++) {
                if constexpr (BDIR) bfr[j] = bd[kk][j];
                else bfr[j] = *(const s8v*)&Bs[(size_t)buf * 128 * BK +
                                               (((wn >> 4) + j) * KG + kk * 4 + quad) * 128 + lm * 8];
            }
#pragma unroll
            for (int i = 0; i < 2; i++)
#pragma unroll
                for (int j = 0; j < 4; j++)
                    acc[i][j] = __builtin_amdgcn_mfma_f32_16x16x32_bf16(af[i], bfr[j], acc[i][j], 0, 0, 0);
        }
        __syncthreads();
    }
    float* Cz = (float*)C + (size_t)blockIdx.z * M * N;
#pragma unroll
    for (int i = 0; i < 2; i++)
#pragma unroll
        for (int j = 0; j < 4; j++) {
            int nn = n0 + wn + j * 16 + lm;
            if (nn >= N) continue;
            float gv = (EPI >= 1) ? g[nn] : 0.f, bv = (EPI >= 1) ? bb[nn] : 0.f;
#pragma unroll
            for (int rr = 0; rr < 4; rr++) {
                int mm = m0 + wm + i * 16 + quad * 4 + rr;
                float v = acc[i][j][rr];
                if (EPI >= 1) v = geluf_(v * gv + bv);
                if (EPI == 2) {
                    int b = mm >> 14, y = (mm >> 7) & 127, x = mm & 127;
                    size_t mp = (size_t)(b * 1024 + (y >> 2) * 32 + (x >> 2));
                    ((bf16*)C)[mp * 2048 + ((y & 3) * 4 + (x & 3)) * 128 + nn] = f2bf(v);
                } else if (CBF) {
                    ((bf16*)C)[(size_t)mm * N + nn] = f2bf(v);
                } else {
                    Cz[(size_t)mm * N + nn] = v;
                }
            }
        }
}

// ---------------- stem split-K reduce + BN + GELU, float4 ----------------
__global__ __launch_bounds__(256) void k_stemred(const float* __restrict__ parts, const float* __restrict__ sp,
                                                 float* __restrict__ tok, ushort_t* __restrict__ tokb) {
    size_t off = ((size_t)blockIdx.x * 256 + threadIdx.x) * 4;
    float4 p0 = *(const float4*)(parts + off);
    float4 p1 = *(const float4*)(parts + 2097152 + off);
    int c = (int)(off & 255);
    const float* gg = sp + SP_G2 + c;
    const float* bp = sp + SP_B2 + c;
    float v0 = geluf_((p0.x + p1.x) * gg[0] + bp[0]);
    float v1 = geluf_((p0.y + p1.y) * gg[1] + bp[1]);
    float v2 = geluf_((p0.z + p1.z) * gg[2] + bp[2]);
    float v3 = geluf_((p0.w + p1.w) * gg[3] + bp[3]);
    float4 o;
    o.x = v0; o.y = v1; o.z = v2; o.w = v3;
    *(float4*)(tok + off) = o;
    u4v ob;
    ob[0] = f2bfs(v0); ob[1] = f2bfs(v1); ob[2] = f2bfs(v2); ob[3] = f2bfs(v3);
    *(u4v*)(tokb + off) = ob;
}

// ---------------- scan1: dwconv+SiLU + chunk scan, 256x512 shape (all heads/block) ----------------
__global__ __launch_bounds__(512, 2) void k_scan1(const bf16* __restrict__ zx, const float* __restrict__ sp,
                                                  float* __restrict__ Sbuf, float* __restrict__ Pbuf,
                                                  int layer) {
    int bid = blockIdx.x;
    int c = bid & 31;
    int b = bid >> 5;
    int tid = threadIdx.x;
    int h = tid >> 6, p = tid & 63;
    __shared__ __align__(16) ushort_t zraw[35 * 512];
    __shared__ __align__(16) ushort_t braw[35 * 32];
    __shared__ __align__(16) float bc_s[CHUNK * 32];
    __shared__ float da_s[8 * CHUNK], dt_s[8 * CHUNK];
    const ushort_t* zxB = (const ushort_t*)zx + (size_t)b * 1024 * 1064;
    int t0 = c * CHUNK;

#pragma unroll
    for (int k = 0; k < 5; k++) {
        int j = tid + k * 512;
        if (j < 2240) {
            int row = j >> 6, c8 = j & 63;
            int t = t0 - 3 + row;
            u8v v = (u8v)0;
            if (t >= 0) v = *(const u8v*)(zxB + (size_t)t * 1064 + 512 + c8 * 8);
            *(u8v*)&zraw[row * 512 + c8 * 8] = v;
        }
    }
    if (tid < 140) {
        int row = tid >> 2, c8 = tid & 3;
        int t = t0 - 3 + row;
        u8v v = (u8v)0;
        if (t >= 0) v = *(const u8v*)(zxB + (size_t)t * 1064 + 1024 + c8 * 8);
        *(u8v*)&braw[row * 32 + c8 * 8] = v;
    }
    if (tid < 256) {
        int tt = tid >> 3, hh = tid & 7;
        float raw = bf2f(zx[(size_t)(b * 1024 + t0 + tt) * 1064 + 1056 + hh]) + sp[SP_DTB + layer * 8 + hh];
        float dtv = raw > 20.f ? raw : log1pf(expf(raw));
        float a = expf(sp[SP_ALOG + layer * 8 + hh]);
        dt_s[hh * 32 + tt] = dtv;
        da_s[hh * 32 + tt] = expf(-dtv * a);
    }
    __syncthreads();

    float xs[CHUNK];
    {
        float4 w4 = *(const float4*)(sp + SP_CONVW + (size_t)(layer * 544 + tid) * 4);
        float bias = sp[SP_CONVB + layer * 544 + tid];
#pragma unroll
        for (int tt = 0; tt < CHUNK; tt++) {
            float acc = bias + us2f(zraw[tt * 512 + tid]) * w4.x + us2f(zraw[(tt + 1) * 512 + tid]) * w4.y +
                        us2f(zraw[(tt + 2) * 512 + tid]) * w4.z + us2f(zraw[(tt + 3) * 512 + tid]) * w4.w;
            xs[tt] = acc * sigmoidf_(acc);
        }
    }
    if (tid < 32) {
        float4 w4 = *(const float4*)(sp + SP_CONVW + (size_t)(layer * 544 + 512 + tid) * 4);
        float bias = sp[SP_CONVB + layer * 544 + 512 + tid];
        int n = tid & 15;
        int slot = (tid < 16) ? 2 * n : 2 * n + 1;
#pragma unroll
        for (int tt = 0; tt < CHUNK; tt++) {
            float acc = bias + us2f(braw[tt * 32 + tid]) * w4.x + us2f(braw[(tt + 1) * 32 + tid]) * w4.y +
                        us2f(braw[(tt + 2) * 32 + tid]) * w4.z + us2f(braw[(tt + 3) * 32 + tid]) * w4.w;
            bc_s[tt * 32 + slot] = acc * sigmoidf_(acc);
        }
    }
    __syncthreads();

    float hs[16];
#pragma unroll
    for (int n = 0; n < 16; n++) hs[n] = 0.f;
    float P = 1.f;
#pragma unroll
    for (int tt = 0; tt < CHUNK; tt++) {
        float dAv = da_s[h * 32 + tt], dtv = dt_s[h * 32 + tt];
        P *= dAv;
        float dtx = xs[tt] * dtv;
        const float4* bcp = (const float4*)&bc_s[tt * 32];
#pragma unroll
        for (int j = 0; j < 8; j++) {
            float4 v = bcp[j];
            hs[2 * j] = hs[2 * j] * dAv + dtx * v.x;
            hs[2 * j + 1] = hs[2 * j + 1] * dAv + dtx * v.z;
        }
    }
    float* So = Sbuf + ((size_t)(b * 8 + h) * 32 + c) * 1024;
#pragma unroll
    for (int n = 0; n < 16; n++) So[n * 64 + p] = hs[n];
    if (p == 0) Pbuf[(b * 8 + h) * 32 + c] = P;
}

// scan2: exclusive prefix over chunks, Sbuf -> Hbuf. 256 blocks x 256 thr.
__global__ __launch_bounds__(256) void k_scan2(const float* __restrict__ Sbuf, const float* __restrict__ Pbuf,
                                               float* __restrict__ Hbuf) {
    int bh = blockIdx.x >> 2;
    int e = ((blockIdx.x & 3) << 8) + threadIdx.x;
    const float* Sp = Sbuf + (size_t)bh * NCH * 1024 + e;
    float* Hp = Hbuf + (size_t)bh * NCH * 1024 + e;
    float hh = 0.f;
#pragma unroll
    for (int gq = 0; gq < 4; gq++) {
        float s[8];
#pragma unroll
        for (int c2 = 0; c2 < 8; c2++) s[c2] = Sp[(size_t)(gq * 8 + c2) * 1024];
#pragma unroll
        for (int c2 = 0; c2 < 8; c2++) {
            Hp[(size_t)(gq * 8 + c2) * 1024] = hh;
            float P = Pbuf[bh * NCH + gq * 8 + c2];
            hh = P * hh + s[c2];
        }
    }
}

// ---------------- scan3go: final scan + gating/RMS + out_proj GEMM + residual/LN ----------------
__global__ __launch_bounds__(512, 2) void k_scan3go(const bf16* __restrict__ zx,
                                                    const float* __restrict__ Hbuf,
                                                    const float* __restrict__ sp,
                                                    const ushort_t* __restrict__ Wt,
                                                    float* __restrict__ tok, ushort_t* __restrict__ tokb,
                                                    int layer) {
    int bid = blockIdx.x;
    int c = bid & 31;
    int b = bid >> 5;
    int tid = threadIdx.x;
    int h = tid >> 6, p = tid & 63;
    __shared__ __align__(16) ushort_t zraw[35 * 512];
    __shared__ __align__(16) ushort_t braw[35 * 32];
    __shared__ __align__(16) float bc_s[CHUNK * 32];
    __shared__ float da_s[8 * CHUNK], dt_s[8 * CHUNK];
    const ushort_t* zxB = (const ushort_t*)zx + (size_t)b * 1024 * 1064;
    int t0 = c * CHUNK;

#pragma unroll
    for (int k = 0; k < 5; k++) {
        int j = tid + k * 512;
        if (j < 2240) {
            int row = j >> 6, c8 = j & 63;
            int t = t0 - 3 + row;
            u8v v = (u8v)0;
            if (t >= 0) v = *(const u8v*)(zxB + (size_t)t * 1064 + 512 + c8 * 8);
            *(u8v*)&zraw[row * 512 + c8 * 8] = v;
        }
    }
    if (tid < 140) {
        int row = tid >> 2, c8 = tid & 3;
        int t = t0 - 3 + row;
        u8v v = (u8v)0;
        if (t >= 0) v = *(const u8v*)(zxB + (size_t)t * 1064 + 1024 + c8 * 8);
        *(u8v*)&braw[row * 32 + c8 * 8] = v;
    }
    if (tid < 256) {
        int tt = tid >> 3, hh = tid & 7;
        float raw = bf2f(zx[(size_t)(b * 1024 + t0 + tt) * 1064 + 1056 + hh]) + sp[SP_DTB + layer * 8 + hh];
        float dtv = raw > 20.f ? raw : log1pf(expf(raw));
        float a = expf(sp[SP_ALOG + layer * 8 + hh]);
        dt_s[hh * 32 + tt] = dtv;
        da_s[hh * 32 + tt] = expf(-dtv * a);
    }
    __syncthreads();

    float xs[CHUNK];
    {
        float4 w4 = *(const float4*)(sp + SP_CONVW + (size_t)(layer * 544 + tid) * 4);
        float bias = sp[SP_CONVB + layer * 544 + tid];
#pragma unroll
        for (int tt = 0; tt < CHUNK; tt++) {
            float acc = bias + us2f(zraw[tt * 512 + tid]) * w4.x + us2f(zraw[(tt + 1) * 512 + tid]) * w4.y +
                        us2f(zraw[(tt + 2) * 512 + tid]) * w4.z + us2f(zraw[(tt + 3) * 512 + tid]) * w4.w;
            xs[tt] = acc * sigmoidf_(acc);
        }
    }
    if (tid < 32) {
        float4 w4 = *(const float4*)(sp + SP_CONVW + (size_t)(layer * 544 + 512 + tid) * 4);
        float bias = sp[SP_CONVB + layer * 544 + 512 + tid];
        int n = tid & 15;
        int slot = (tid < 16) ? 2 * n : 2 * n + 1;
#pragma unroll
        for (int tt = 0; tt < CHUNK; tt++) {
            float acc = bias + us2f(braw[tt * 32 + tid]) * w4.x + us2f(braw[(tt + 1) * 32 + tid]) * w4.y +
                        us2f(braw[(tt + 2) * 32 + tid]) * w4.z + us2f(braw[(tt + 3) * 32 + tid]) * w4.w;
            bc_s[tt * 32 + slot] = acc * sigmoidf_(acc);
        }
    }

    float hs[16];
    {
        const float* Si = Hbuf + ((size_t)(b * 8 + h) * 32 + c) * 1024;
#pragma unroll
        for (int n = 0; n < 16; n++) hs[n] = Si[n * 64 + p];
    }
    float dsk = sp[SP_DSK + layer * 8 + h];
    __syncthreads();  // bc_s ready; all conv reads of zraw done (x-raw now dead)

    // ---- final scan, y (bf16-rounded) -> y_s[32][YST] (zraw reuse) ----
    ushort_t* y_s = zraw;
#pragma unroll
    for (int tt = 0; tt < CHUNK; tt++) {
        float dAv = da_s[h * 32 + tt], dtv = dt_s[h * 32 + tt];
        float dtx = xs[tt] * dtv;
        float acc = 0.f;
        const float4* bcp = (const float4*)&bc_s[tt * 32];
#pragma unroll
        for (int j = 0; j < 8; j++) {
            float4 v = bcp[j];
            hs[2 * j] = hs[2 * j] * dAv + dtx * v.x;
            acc += hs[2 * j] * v.y;
            hs[2 * j + 1] = hs[2 * j + 1] * dAv + dtx * v.z;
            acc += hs[2 * j + 1] * v.w;
        }
        y_s[tt * YST + tid] = f2bfs(acc + xs[tt] * dsk);
    }
    __syncthreads();

    // ---- gating + RMSNorm in place; wave h handles rows h*4..h*4+3 ----
    {
        int lane = p;
        float4 rw0 = *(const float4*)(sp + SP_RMSW + layer * 512 + lane * 8);
        float4 rw1 = *(const float4*)(sp + SP_RMSW + layer * 512 + lane * 8 + 4);
        float rwv[8] = {rw0.x, rw0.y, rw0.z, rw0.w, rw1.x, rw1.y, rw1.z, rw1.w};
#pragma unroll
        for (int r = 0; r < 4; r++) {
            int tt = h * 4 + r;
            u8v yv = *(const u8v*)&y_s[tt * YST + lane * 8];
            u8v zv = *(const u8v*)(zxB + (size_t)(t0 + tt) * 1064 + lane * 8);
            float t[8];
            float ss = 0.f;
#pragma unroll
            for (int j2 = 0; j2 < 8; j2++) {
                float z = us2f(zv[j2]);
                float yy = us2f(yv[j2]);
                float tv = yy * (z * sigmoidf_(z));
                t[j2] = tv;
                ss += tv * tv;
            }
#pragma unroll
            for (int d = 32; d; d >>= 1) ss += __shfl_xor(ss, d, 64);
            float scale = rsqrtf(ss * (1.f / 512.f) + 1e-5f);
            u8v o;
#pragma unroll
            for (int j2 = 0; j2 < 8; j2++) o[j2] = f2bfs(t[j2] * scale * rwv[j2]);
            *(u8v*)&y_s[tt * YST + lane * 8] = o;
        }
    }
    __syncthreads();

    // ---- out_proj GEMM: C[32][256] = y_s[32][512] @ Wt[n][k]^T; wave h -> cols h*32.. ----
    int lm = p & 15, quad = p >> 4;
    f4v acc2[2][2];
#pragma unroll
    for (int mi = 0; mi < 2; mi++)
#pragma unroll
        for (int ni = 0; ni < 2; ni++) acc2[mi][ni] = (f4v){0.f, 0.f, 0.f, 0.f};
#pragma unroll
    for (int kk = 0; kk < 16; kk++) {
        s8v af[2], bw[2];
#pragma unroll
        for (int mi = 0; mi < 2; mi++)
            af[mi] = *(const s8v*)&y_s[(mi * 16 + lm) * YST + kk * 32 + quad * 8];
#pragma unroll
        for (int ni = 0; ni < 2; ni++)
            bw[ni] = *(const s8v*)(Wt + (size_t)(h * 32 + ni * 16 + lm) * 512 + kk * 32 + quad * 8);
#pragma unroll
        for (int mi = 0; mi < 2; mi++)
#pragma unroll
            for (int ni = 0; ni < 2; ni++)
                acc2[mi][ni] = __builtin_amdgcn_mfma_f32_16x16x32_bf16(af[mi], bw[ni], acc2[mi][ni], 0, 0, 0);
    }
    __syncthreads();  // all y_s reads complete before C_lds overwrite

    float* C_lds = (float*)zraw;  // [32][260]
#pragma unroll
    for (int mi = 0; mi < 2; mi++)
#pragma unroll
        for (int ni = 0; ni < 2; ni++)
#pragma unroll
            for (int rr = 0; rr < 4; rr++)
                C_lds[(mi * 16 + quad * 4 + rr) * 260 + h * 32 + ni * 16 + lm] = acc2[mi][ni][rr];
    __syncthreads();

    // ---- residual + LayerNorm; wave h rows h*4..h*4+3 ----
#pragma unroll
    for (int r = 0; r < 4; r++) {
        int tt = h * 4 + r;
        size_t off = (size_t)(b * 1024 + t0 + tt) * 256 + p * 4;
        float4 v = *(const float4*)(tok + off);
        float4 cv = *(const float4*)&C_lds[tt * 260 + p * 4];
        v.x += cv.x;
        v.y += cv.y;
        v.z += cv.z;
        v.w += cv.w;
        float s = v.x + v.y + v.z + v.w;
#pragma unroll
        for (int d = 32; d; d >>= 1) s += __shfl_xor(s, d, 64);
        float mean = s * (1.f / 256.f);
        float dx = v.x - mean, dy = v.y - mean, dz = v.z - mean, dw = v.w - mean;
        float ss = dx * dx + dy * dy + dz * dz + dw * dw;
#pragma unroll
        for (int d = 32; d; d >>= 1) ss += __shfl_xor(ss, d, 64);
        float inv = rsqrtf(ss * (1.f / 256.f) + 1e-5f);
        const float* lg = sp + SP_LNG + layer * 256 + p * 4;
        const float* lb = sp + SP_LNB + layer * 256 + p * 4;
        float r0 = dx * inv * lg[0] + lb[0];
        float r1 = dy * inv * lg[1] + lb[1];
        float r2 = dz * inv * lg[2] + lb[2];
        float r3 = dw * inv * lg[3] + lb[3];
        float4 rv;
        rv.x = r0; rv.y = r1; rv.z = r2; rv.w = r3;
        *(float4*)(tok + off) = rv;
        u4v ob;
        ob[0] = f2bfs(r0); ob[1] = f2bfs(r1); ob[2] = f2bfs(r2); ob[3] = f2bfs(r3);
        *(u4v*)(tokb + off) = ob;
    }
}

// ---------------- block reduction helper (head only) ----------------
DEV float block_sum256(float v, float* s4) {
#pragma unroll
    for (int off = 32; off; off >>= 1) v += __shfl_down(v, off, 64);
    __syncthreads();
    if ((threadIdx.x & 63) == 0) s4[threadIdx.x >> 6] = v;
    __syncthreads();
    return s4[0] + s4[1] + s4[2] + s4[3];
}

// ---------------- mean pool stage 1 ----------------
__global__ void k_pool1(const float* __restrict__ tok, float* __restrict__ ppart) {
    int b = blockIdx.x >> 4, chunk = blockIdx.x & 15;
    int c = threadIdx.x;
    float s = 0.f;
    for (int t = 0; t < 64; t++) s += tok[((size_t)b * 1024 + chunk * 64 + t) * 256 + c];
    ppart[(size_t)blockIdx.x * 256 + c] = s;
}

// ---------------- head (pool stage 2 fused) ----------------
__global__ __launch_bounds__(256) void k_head(const float* __restrict__ ppart, const float* __restrict__ sp,
                                              void* __restrict__ out, const void* __restrict__ g1) {
    __shared__ float s4[4];
    __shared__ float lds[256];
    int md = mode_of(g1);
    int b = blockIdx.x;
    int c = threadIdx.x;
    float v = 0.f;
#pragma unroll
    for (int k = 0; k < 16; k++) v += ppart[(size_t)(b * 16 + k) * 256 + c];
    v *= (1.f / 1024.f);
    float mean = block_sum256(v, s4) * (1.f / 256.f);
    float d = v - mean;
    float var = block_sum256(d * d, s4) * (1.f / 256.f);
    lds[c] = d * rsqrtf(var + 1e-5f) * sp[SP_HLG + c] + sp[SP_HLB + c];
    __syncthreads();
    if (c < 10) {
        float s = sp[SP_HB + c];
        for (int k = 0; k < 256; k++) s += lds[k] * sp[SP_HW + k * 10 + c];
        if (md)
            ((bf16*)out)[b * 10 + c] = f2bf(s);
        else
            ((float*)out)[b * 10 + c] = s;
    }
}

extern "C" void kernel_launch(void* const* d_in, const int* in_sizes, int n_in, void* d_out, int out_size,
                              void* d_ws, size_t ws_size, hipStream_t stream) {
    const void* x         = d_in[0];
    const void* stem_w1   = d_in[1];
    const void* stem_g1   = d_in[2];
    const void* stem_b1   = d_in[3];
    const void* stem_w2   = d_in[4];
    const void* stem_g2   = d_in[5];
    const void* stem_b2   = d_in[6];
    const void* in_w      = d_in[7];
    const void* conv_w    = d_in[8];
    const void* conv_b    = d_in[9];
    const void* dt_bias   = d_in[10];
    const void* A_log     = d_in[11];
    const void* D_skip    = d_in[12];
    const void* rms_w     = d_in[13];
    const void* out_w     = d_in[14];
    const void* ln_g      = d_in[15];
    const void* ln_b      = d_in[16];
    const void* head_ln_g = d_in[17];
    const void* head_ln_b = d_in[18];
    const void* head_w    = d_in[19];
    const void* head_b    = d_in[20];

    // ---- workspace layout (float units), ~99 MB ----
    float* ws     = (float*)d_ws;
    float* tok    = ws;                        // 2,097,152 f
    float* mbuf   = ws + 2097152;              // 2,097,152 f (Sbuf scan scratch)
    float* Hbuf   = ws + 4194304;              // 2,097,152 f
    float* parts  = ws + 6291456;              // 8,388,608 f (split-K partials, stem only)
    float* ppart  = ws + 14682112;             // 32,768 f
    float* Pbuf   = ws + 14714880;             // 2,048 f
    float* sp     = ws + 14716944;             // 18,944 f
    ushort_t* tokb = (ushort_t*)(ws + 14735888);  // 2,097,152 e
    ushort_t* wT  = (ushort_t*)(ws + 15784464);   // 2,142,208 e
    ushort_t* w1T   = wT;
    ushort_t* w2T   = wT + 4096;
    ushort_t* inwT  = wT + 528384;
    ushort_t* outwT = wT + 1617920;
    bf16* arena   = (bf16*)(ws + 16855568);    // 17,367,040 e
    bf16* zx      = arena;                     // 8,716,288 e
    ushort_t* patch = (ushort_t*)arena;        // 16,777,216 e (dead before zx)
    float* Sbuf    = mbuf;                     // scan scratch

    k_prep<<<(SP_TOTAL + 2142208 + 255) / 256, 256, 0, stream>>>(
        conv_w, conv_b, dt_bias, A_log, D_skip, rms_w, ln_g, ln_b, head_ln_g, head_ln_b, head_w, head_b,
        stem_g1, stem_b1, stem_g2, stem_b2, stem_w1, stem_w2, in_w, out_w, sp, wT);

    // stem: conv1 (inline im2col, patch-layout out), conv2 split-K 2 (B direct), reduce(+BN+GELU)
    k_gemmT<2, 1, 32, 1, 0><<<dim3(1, 2048, 1), 256, 0, stream>>>(
        (const ushort_t*)x, w1T, patch, 131072, 128, 32, 32, sp + SP_G1, sp + SP_B1, x, stem_g1);
    k_gemmT<0, 0, 64, 0, 1><<<dim3(2, 128, 2), 256, 0, stream>>>(
        patch, w2T, parts, 8192, 256, 2048, 1024, nullptr, nullptr, nullptr, nullptr);
    k_stemred<<<2048, 256, 0, stream>>>(parts, sp, tok, tokb);

    for (int l = 0; l < 4; l++) {
        k_gemmT<0, 1, 64, 0, 1><<<dim3(9, 128, 1), 256, 0, stream>>>(
            tokb, inwT + (size_t)l * 272384, zx, 8192, 1064, 256, 256, nullptr, nullptr, nullptr, nullptr);
        k_scan1<<<256, 512, 0, stream>>>(zx, sp, Sbuf, Pbuf, l);
        k_scan2<<<256, 256, 0, stream>>>(Sbuf, Pbuf, Hbuf);
        k_scan3go<<<256, 512, 0, stream>>>(zx, Hbuf, sp, outwT + (size_t)l * 131072, tok, tokb, l);
    }

    k_pool1<<<128, 256, 0, stream>>>(tok, ppart);
    k_head<<<8, 256, 0, stream>>>(ppart, sp, d_out, stem_g1);
}

// Round 13
// 438.836 us; speedup vs baseline: 1.1173x; 1.1173x over previous
//
#include <hip/hip_runtime.h>
#include <hip/hip_bf16.h>

// Mamba2 vision model, MI355X. 64x128-tile bf16 MFMA GEMMs (3 blocks/CU),
// split-K for conv2; conv1 computes im2col INLINE in its A-staging (IMC arm)
// and writes conv2's patch layout directly. Split scan kernels (r2/r5/r6:
// barrier-fused shape ~2x slower structurally). scan1 uses scan3go's
// 256x512 shape (B/C conv + dt dedup'd 8x across heads). k_scan3go fuses
// final scan + gating/RMS + out_proj GEMM + residual/LN (r10: -21us, the
// 32x512 gated-y tile is a complete M-tile in LDS; stride-520 -> 2-way bank
// rotation free). r12 lesson: direct-from-L2 B-frags in the main GEMM loop
// are uncoalesced per-lane gathers -> +11%; LDS staging stays.
// Shapes: B=8, L=1024, D_MODEL=256, D_INNER=512, NHEADS=8, HEADDIM=64,
// D_STATE=16, CONV_DIM=544, D_IN_PROJ=1064, N_LAYERS=4.

#define DEV __device__ __forceinline__
typedef __hip_bfloat16 bf16;
typedef unsigned short ushort_t;
typedef __attribute__((ext_vector_type(8))) short s8v;
typedef __attribute__((ext_vector_type(8))) unsigned short u8v;
typedef __attribute__((ext_vector_type(4))) unsigned short u4v;
typedef __attribute__((ext_vector_type(4))) float f4v;

#define CHUNK 32
#define NCH 32
#define YST 520   // y_s / C_lds row stride (bf16 units / +4-bank rotation)

// small-param fp32 scratch offsets
#define SP_CONVW 0
#define SP_CONVB 8704
#define SP_DTB   10880
#define SP_ALOG  10912
#define SP_DSK   10944
#define SP_RMSW  10976
#define SP_LNG   13024
#define SP_LNB   14048
#define SP_HLG   15072
#define SP_HLB   15328
#define SP_HW    15584
#define SP_HB    18144
#define SP_G1    18160
#define SP_B1    18288
#define SP_G2    18416
#define SP_B2    18672
#define SP_TOTAL 18928

DEV float bf2f(bf16 h) { return __bfloat162float(h); }
DEV bf16 f2bf(float f) { return __float2bfloat16(f); }
DEV float us2f(ushort_t u) { return __uint_as_float(((unsigned int)u) << 16); }
DEV ushort_t f2bfs(float f) {
    unsigned int u = __float_as_uint(f);
    return (ushort_t)((u + 0x7FFFu + ((u >> 16) & 1u)) >> 16);
}
DEV float ldf(const void* p, size_t i, int bf) {
    return bf ? us2f(((const ushort_t*)p)[i]) : ((const float*)p)[i];
}
DEV ushort_t ldbf(const void* p, size_t i, int bf) {
    return bf ? ((const ushort_t*)p)[i] : f2bfs(((const float*)p)[i]);
}
DEV int mode_of(const void* g1) { return (((const unsigned int*)g1)[0] == 0x3F800000u) ? 0 : 1; }
DEV float sigmoidf_(float x) { return 1.f / (1.f + __expf(-x)); }
DEV float geluf_(float x) { return 0.5f * x * (1.f + erff(x * 0.70710678118654752f)); }

// ---------------- merged: small params -> fp32 scratch + weight transpose ----------------
__global__ void k_prep(const void* cw, const void* cb, const void* dtb, const void* alog,
                       const void* dsk, const void* rmsw, const void* lng, const void* lnb,
                       const void* hlg, const void* hlb, const void* hw, const void* hb,
                       const void* g1, const void* b1, const void* g2, const void* b2,
                       const void* w1, const void* w2, const void* inw, const void* outw,
                       float* __restrict__ sp, ushort_t* __restrict__ wT) {
    int md = mode_of(g1);
    int i = blockIdx.x * 256 + threadIdx.x;
    if (i < SP_TOTAL) {
        float v;
        if (i < SP_CONVB) v = ldf(cw, i, md);
        else if (i < SP_DTB) v = ldf(cb, i - SP_CONVB, md);
        else if (i < SP_ALOG) v = ldf(dtb, i - SP_DTB, md);
        else if (i < SP_DSK) v = ldf(alog, i - SP_ALOG, md);
        else if (i < SP_RMSW) v = ldf(dsk, i - SP_DSK, md);
        else if (i < SP_LNG) v = ldf(rmsw, i - SP_RMSW, md);
        else if (i < SP_LNB) v = ldf(lng, i - SP_LNG, md);
        else if (i < SP_HLG) v = ldf(lnb, i - SP_LNB, md);
        else if (i < SP_HLB) v = ldf(hlg, i - SP_HLG, md);
        else if (i < SP_HW) v = ldf(hlb, i - SP_HLB, md);
        else if (i < SP_HB) v = ldf(hw, i - SP_HW, md);
        else if (i < SP_G1) v = (i - SP_HB < 10) ? ldf(hb, i - SP_HB, md) : 0.f;
        else if (i < SP_B1) v = ldf(g1, i - SP_G1, md);
        else if (i < SP_G2) v = ldf(b1, i - SP_B1, md);
        else if (i < SP_B2) v = ldf(g2, i - SP_G2, md);
        else v = ldf(b2, i - SP_B2, md);
        sp[i] = v;
        return;
    }
    int iw = i - SP_TOTAL;
    if (iw >= 2142208) return;
    ushort_t v;
    if (iw < 4096) {
        int oc = iw >> 5, k = iw & 31;
        v = (k < 27) ? ldbf(w1, (size_t)oc * 27 + k, md) : 0;
    } else if (iw < 528384) {
        int j = iw - 4096;
        int oc = j >> 11, k = j & 2047;
        int c = k & 127, kykx = k >> 7;
        v = ldbf(w2, (size_t)(oc * 128 + c) * 16 + kykx, md);
    } else if (iw < 1617920) {
        int j = iw - 528384;
        int l = j / 272384, r = j % 272384;
        int n = r >> 8, k = r & 255;
        v = ldbf(inw, (size_t)l * 272384 + (size_t)k * 1064 + n, md);
    } else {
        int j = iw - 1617920;
        int l = j >> 17, r = j & 131071;
        int n = r >> 9, k = r & 511;
        v = ldbf(outw, (size_t)l * 131072 + (size_t)k * 256 + n, md);
    }
    wT[iw] = v;
}

// ---------------- bf16 MFMA GEMM, 64x128 tile, dbuf LDS, split-K capable ----------------
// A: bf16 [m][k] stride K (or IMC=1: A-values computed inline as conv1 im2col
// from xsrc, dtype via g1p). Wt: bf16 [n][k] stride K.
// EPI 0: plain write (CBF picks bf16/fp32; fp32 -> C + z*M*N split-K).
// EPI 1: gelu(g[n]*v+b[n]) bf16. EPI 2: BN+GELU + conv2-patch-layout write.
template <int EPI, int CBF, int BK, int IMC>
__global__ __launch_bounds__(256, 3) void k_gemmT(const ushort_t* __restrict__ A,
                                                  const ushort_t* __restrict__ Wt, void* __restrict__ C,
                                                  int M, int N, int K, int klen,
                                                  const float* __restrict__ g, const float* __restrict__ bb,
                                                  const void* __restrict__ xsrc,
                                                  const void* __restrict__ g1p) {
    constexpr int KG = BK / 8;
    constexpr int EA = BK / 4;
    constexpr int EB = BK / 2;
    constexpr int AU = EA / 8;
    constexpr int BU = EB / 8;
    __shared__ __align__(16) ushort_t As[2][64 * BK];
    __shared__ __align__(16) ushort_t Bs[2][128 * BK];
    int tid = threadIdx.x;
    int m0 = blockIdx.y * 64, n0 = blockIdx.x * 128;
    int koff = blockIdx.z * klen;
    int w = tid >> 6, lane = tid & 63;
    int wm = (w >> 1) * 32, wn = (w & 1) * 64;
    int lm = lane & 15, quad = lane >> 4;
    int ar = tid >> 2, ak = (tid & 3) * EA;
    int br = tid >> 1, bk = (tid & 1) * EB;
    bool bvalid = (n0 + br) < N;
    int md = 0;
    if constexpr (IMC) md = mode_of(g1p);

    u8v pa[AU], pb[BU];
    auto loadT = [&](int kb) {
        if constexpr (IMC) {
            // conv1 im2col on the fly: row m = pixel, k = ci*9+dy*3+dx (27 taps)
            int m = m0 + ar;
            int xx2 = m & 127, yy2 = (m >> 7) & 127, bb2 = m >> 14;
            u8v v = (u8v)0;
#pragma unroll
            for (int j = 0; j < 8; j++) {
                int k = ak + j;
                if (k < 27) {
                    int ci = k / 9, r2 = k - ci * 9;
                    int dy = r2 / 3, dx = r2 - dy * 3;
                    int sy = yy2 + dy - 1, sx = xx2 + dx - 1;
                    if (sy >= 0 && sy < 128 && sx >= 0 && sx < 128) {
                        size_t idx = ((size_t)(bb2 * 3 + ci) * 128 + sy) * 128 + sx;
                        v[j] = md ? ((const ushort_t*)xsrc)[idx] : f2bfs(((const float*)xsrc)[idx]);
                    }
                }
            }
            pa[0] = v;
        } else {
            const u8v* ap = (const u8v*)(A + (size_t)(m0 + ar) * K + koff + kb + ak);
#pragma unroll
            for (int j = 0; j < AU; j++) pa[j] = ap[j];
        }
        if (bvalid) {
            const u8v* bp = (const u8v*)(Wt + (size_t)(n0 + br) * K + koff + kb + bk);
#pragma unroll
            for (int j = 0; j < BU; j++) pb[j] = bp[j];
        } else {
#pragma unroll
            for (int j = 0; j < BU; j++) pb[j] = (u8v)0;
        }
    };
    auto storeT = [&](int buf) {
        int ag = ak >> 3;
#pragma unroll
        for (int j = 0; j < AU; j++)
            *(u8v*)&As[buf][((ar >> 4) * KG + ag + j) * 128 + (ar & 15) * 8] = pa[j];
        int bg = bk >> 3;
#pragma unroll
        for (int j = 0; j < BU; j++)
            *(u8v*)&Bs[buf][((br >> 4) * KG + bg + j) * 128 + (br & 15) * 8] = pb[j];
    };

    f4v acc[2][4];
#pragma unroll
    for (int i = 0; i < 2; i++)
#pragma unroll
        for (int j = 0; j < 4; j++) acc[i][j] = (f4v){0.f, 0.f, 0.f, 0.f};

    int niter = klen / BK;
    loadT(0);
    storeT(0);
    if (niter > 1) loadT(BK);
    __syncthreads();
    for (int it = 0; it < niter; it++) {
        int buf = it & 1;
        if (it + 1 < niter) {
            storeT(buf ^ 1);
            if (it + 2 < niter) loadT((it + 2) * BK);
        }
#pragma unroll
        for (int kk = 0; kk < BK / 32; kk++) {
            s8v af[2], bfr[4];
#pragma unroll
            for (int i = 0; i < 2; i++)
                af[i] = *(const s8v*)&As[buf][(((wm >> 4) + i) * KG + kk * 4 + quad) * 128 + lm * 8];
#pragma unroll
            for (int j = 0; j < 4; j++)
                bfr[j] = *(const s8v*)&Bs[buf][(((wn >> 4) + j) * KG + kk * 4 + quad) * 128 + lm * 8];
#pragma unroll
            for (int i = 0; i < 2; i++)
#pragma unroll
                for (int j = 0; j < 4; j++)
                    acc[i][j] = __builtin_amdgcn_mfma_f32_16x16x32_bf16(af[i], bfr[j], acc[i][j], 0, 0, 0);
        }
        __syncthreads();
    }
    float* Cz = (float*)C + (size_t)blockIdx.z * M * N;
#pragma unroll
    for (int i = 0; i < 2; i++)
#pragma unroll
        for (int j = 0; j < 4; j++) {
            int nn = n0 + wn + j * 16 + lm;
            if (nn >= N) continue;
            float gv = (EPI >= 1) ? g[nn] : 0.f, bv = (EPI >= 1) ? bb[nn] : 0.f;
#pragma unroll
            for (int rr = 0; rr < 4; rr++) {
                int mm = m0 + wm + i * 16 + quad * 4 + rr;
                float v = acc[i][j][rr];
                if (EPI >= 1) v = geluf_(v * gv + bv);
                if (EPI == 2) {
                    int b = mm >> 14, y = (mm >> 7) & 127, x = mm & 127;
                    size_t mp = (size_t)(b * 1024 + (y >> 2) * 32 + (x >> 2));
                    ((bf16*)C)[mp * 2048 + ((y & 3) * 4 + (x & 3)) * 128 + nn] = f2bf(v);
                } else if (CBF) {
                    ((bf16*)C)[(size_t)mm * N + nn] = f2bf(v);
                } else {
                    Cz[(size_t)mm * N + nn] = v;
                }
            }
        }
}

// ---------------- stem split-K reduce + BN + GELU, float4 ----------------
__global__ __launch_bounds__(256) void k_stemred(const float* __restrict__ parts, const float* __restrict__ sp,
                                                 float* __restrict__ tok, ushort_t* __restrict__ tokb) {
    size_t off = ((size_t)blockIdx.x * 256 + threadIdx.x) * 4;
    float4 p0 = *(const float4*)(parts + off);
    float4 p1 = *(const float4*)(parts + 2097152 + off);
    int c = (int)(off & 255);
    const float* gg = sp + SP_G2 + c;
    const float* bp = sp + SP_B2 + c;
    float v0 = geluf_((p0.x + p1.x) * gg[0] + bp[0]);
    float v1 = geluf_((p0.y + p1.y) * gg[1] + bp[1]);
    float v2 = geluf_((p0.z + p1.z) * gg[2] + bp[2]);
    float v3 = geluf_((p0.w + p1.w) * gg[3] + bp[3]);
    float4 o;
    o.x = v0; o.y = v1; o.z = v2; o.w = v3;
    *(float4*)(tok + off) = o;
    u4v ob;
    ob[0] = f2bfs(v0); ob[1] = f2bfs(v1); ob[2] = f2bfs(v2); ob[3] = f2bfs(v3);
    *(u4v*)(tokb + off) = ob;
}

// ---------------- scan1: dwconv+SiLU + chunk scan, 256x512 shape (all heads/block) ----------------
// Block = (b, chunk); h = tid>>6, p = tid&63. B/C conv + dt dedup'd 8x vs the
// old per-head 2048x64 shape. xs[32] in VGPRs (r4 form; spill latency-hidden).
__global__ __launch_bounds__(512, 2) void k_scan1(const bf16* __restrict__ zx, const float* __restrict__ sp,
                                                  float* __restrict__ Sbuf, float* __restrict__ Pbuf,
                                                  int layer) {
    int bid = blockIdx.x;
    int c = bid & 31;
    int b = bid >> 5;
    int tid = threadIdx.x;
    int h = tid >> 6, p = tid & 63;
    __shared__ __align__(16) ushort_t zraw[35 * 512];
    __shared__ __align__(16) ushort_t braw[35 * 32];
    __shared__ __align__(16) float bc_s[CHUNK * 32];
    __shared__ float da_s[8 * CHUNK], dt_s[8 * CHUNK];
    const ushort_t* zxB = (const ushort_t*)zx + (size_t)b * 1024 * 1064;
    int t0 = c * CHUNK;

#pragma unroll
    for (int k = 0; k < 5; k++) {
        int j = tid + k * 512;
        if (j < 2240) {
            int row = j >> 6, c8 = j & 63;
            int t = t0 - 3 + row;
            u8v v = (u8v)0;
            if (t >= 0) v = *(const u8v*)(zxB + (size_t)t * 1064 + 512 + c8 * 8);
            *(u8v*)&zraw[row * 512 + c8 * 8] = v;
        }
    }
    if (tid < 140) {
        int row = tid >> 2, c8 = tid & 3;
        int t = t0 - 3 + row;
        u8v v = (u8v)0;
        if (t >= 0) v = *(const u8v*)(zxB + (size_t)t * 1064 + 1024 + c8 * 8);
        *(u8v*)&braw[row * 32 + c8 * 8] = v;
    }
    if (tid < 256) {
        int tt = tid >> 3, hh = tid & 7;
        float raw = bf2f(zx[(size_t)(b * 1024 + t0 + tt) * 1064 + 1056 + hh]) + sp[SP_DTB + layer * 8 + hh];
        float dtv = raw > 20.f ? raw : log1pf(expf(raw));
        float a = expf(sp[SP_ALOG + layer * 8 + hh]);
        dt_s[hh * 32 + tt] = dtv;
        da_s[hh * 32 + tt] = expf(-dtv * a);
    }
    __syncthreads();

    float xs[CHUNK];
    {
        float4 w4 = *(const float4*)(sp + SP_CONVW + (size_t)(layer * 544 + tid) * 4);
        float bias = sp[SP_CONVB + layer * 544 + tid];
#pragma unroll
        for (int tt = 0; tt < CHUNK; tt++) {
            float acc = bias + us2f(zraw[tt * 512 + tid]) * w4.x + us2f(zraw[(tt + 1) * 512 + tid]) * w4.y +
                        us2f(zraw[(tt + 2) * 512 + tid]) * w4.z + us2f(zraw[(tt + 3) * 512 + tid]) * w4.w;
            xs[tt] = acc * sigmoidf_(acc);
        }
    }
    if (tid < 32) {
        float4 w4 = *(const float4*)(sp + SP_CONVW + (size_t)(layer * 544 + 512 + tid) * 4);
        float bias = sp[SP_CONVB + layer * 544 + 512 + tid];
        int n = tid & 15;
        int slot = (tid < 16) ? 2 * n : 2 * n + 1;
#pragma unroll
        for (int tt = 0; tt < CHUNK; tt++) {
            float acc = bias + us2f(braw[tt * 32 + tid]) * w4.x + us2f(braw[(tt + 1) * 32 + tid]) * w4.y +
                        us2f(braw[(tt + 2) * 32 + tid]) * w4.z + us2f(braw[(tt + 3) * 32 + tid]) * w4.w;
            bc_s[tt * 32 + slot] = acc * sigmoidf_(acc);
        }
    }
    __syncthreads();

    float hs[16];
#pragma unroll
    for (int n = 0; n < 16; n++) hs[n] = 0.f;
    float P = 1.f;
#pragma unroll
    for (int tt = 0; tt < CHUNK; tt++) {
        float dAv = da_s[h * 32 + tt], dtv = dt_s[h * 32 + tt];
        P *= dAv;
        float dtx = xs[tt] * dtv;
        const float4* bcp = (const float4*)&bc_s[tt * 32];
#pragma unroll
        for (int j = 0; j < 8; j++) {
            float4 v = bcp[j];
            hs[2 * j] = hs[2 * j] * dAv + dtx * v.x;
            hs[2 * j + 1] = hs[2 * j + 1] * dAv + dtx * v.z;
        }
    }
    float* So = Sbuf + ((size_t)(b * 8 + h) * 32 + c) * 1024;
#pragma unroll
    for (int n = 0; n < 16; n++) So[n * 64 + p] = hs[n];
    if (p == 0) Pbuf[(b * 8 + h) * 32 + c] = P;
}

// scan2: exclusive prefix over chunks, Sbuf -> Hbuf. 256 blocks x 256 thr.
__global__ __launch_bounds__(256) void k_scan2(const float* __restrict__ Sbuf, const float* __restrict__ Pbuf,
                                               float* __restrict__ Hbuf) {
    int bh = blockIdx.x >> 2;
    int e = ((blockIdx.x & 3) << 8) + threadIdx.x;
    const float* Sp = Sbuf + (size_t)bh * NCH * 1024 + e;
    float* Hp = Hbuf + (size_t)bh * NCH * 1024 + e;
    float hh = 0.f;
#pragma unroll
    for (int gq = 0; gq < 4; gq++) {
        float s[8];
#pragma unroll
        for (int c2 = 0; c2 < 8; c2++) s[c2] = Sp[(size_t)(gq * 8 + c2) * 1024];
#pragma unroll
        for (int c2 = 0; c2 < 8; c2++) {
            Hp[(size_t)(gq * 8 + c2) * 1024] = hh;
            float P = Pbuf[bh * NCH + gq * 8 + c2];
            hh = P * hh + s[c2];
        }
    }
}

// ---------------- scan3go: final scan + gating/RMS + out_proj GEMM + residual/LN ----------------
__global__ __launch_bounds__(512, 2) void k_scan3go(const bf16* __restrict__ zx,
                                                    const float* __restrict__ Hbuf,
                                                    const float* __restrict__ sp,
                                                    const ushort_t* __restrict__ Wt,
                                                    float* __restrict__ tok, ushort_t* __restrict__ tokb,
                                                    int layer) {
    int bid = blockIdx.x;
    int c = bid & 31;
    int b = bid >> 5;
    int tid = threadIdx.x;
    int h = tid >> 6, p = tid & 63;
    __shared__ __align__(16) ushort_t zraw[35 * 512];
    __shared__ __align__(16) ushort_t braw[35 * 32];
    __shared__ __align__(16) float bc_s[CHUNK * 32];
    __shared__ float da_s[8 * CHUNK], dt_s[8 * CHUNK];
    const ushort_t* zxB = (const ushort_t*)zx + (size_t)b * 1024 * 1064;
    int t0 = c * CHUNK;

#pragma unroll
    for (int k = 0; k < 5; k++) {
        int j = tid + k * 512;
        if (j < 2240) {
            int row = j >> 6, c8 = j & 63;
            int t = t0 - 3 + row;
            u8v v = (u8v)0;
            if (t >= 0) v = *(const u8v*)(zxB + (size_t)t * 1064 + 512 + c8 * 8);
            *(u8v*)&zraw[row * 512 + c8 * 8] = v;
        }
    }
    if (tid < 140) {
        int row = tid >> 2, c8 = tid & 3;
        int t = t0 - 3 + row;
        u8v v = (u8v)0;
        if (t >= 0) v = *(const u8v*)(zxB + (size_t)t * 1064 + 1024 + c8 * 8);
        *(u8v*)&braw[row * 32 + c8 * 8] = v;
    }
    if (tid < 256) {
        int tt = tid >> 3, hh = tid & 7;
        float raw = bf2f(zx[(size_t)(b * 1024 + t0 + tt) * 1064 + 1056 + hh]) + sp[SP_DTB + layer * 8 + hh];
        float dtv = raw > 20.f ? raw : log1pf(expf(raw));
        float a = expf(sp[SP_ALOG + layer * 8 + hh]);
        dt_s[hh * 32 + tt] = dtv;
        da_s[hh * 32 + tt] = expf(-dtv * a);
    }
    __syncthreads();

    float xs[CHUNK];
    {
        float4 w4 = *(const float4*)(sp + SP_CONVW + (size_t)(layer * 544 + tid) * 4);
        float bias = sp[SP_CONVB + layer * 544 + tid];
#pragma unroll
        for (int tt = 0; tt < CHUNK; tt++) {
            float acc = bias + us2f(zraw[tt * 512 + tid]) * w4.x + us2f(zraw[(tt + 1) * 512 + tid]) * w4.y +
                        us2f(zraw[(tt + 2) * 512 + tid]) * w4.z + us2f(zraw[(tt + 3) * 512 + tid]) * w4.w;
            xs[tt] = acc * sigmoidf_(acc);
        }
    }
    if (tid < 32) {
        float4 w4 = *(const float4*)(sp + SP_CONVW + (size_t)(layer * 544 + 512 + tid) * 4);
        float bias = sp[SP_CONVB + layer * 544 + 512 + tid];
        int n = tid & 15;
        int slot = (tid < 16) ? 2 * n : 2 * n + 1;
#pragma unroll
        for (int tt = 0; tt < CHUNK; tt++) {
            float acc = bias + us2f(braw[tt * 32 + tid]) * w4.x + us2f(braw[(tt + 1) * 32 + tid]) * w4.y +
                        us2f(braw[(tt + 2) * 32 + tid]) * w4.z + us2f(braw[(tt + 3) * 32 + tid]) * w4.w;
            bc_s[tt * 32 + slot] = acc * sigmoidf_(acc);
        }
    }

    float hs[16];
    {
        const float* Si = Hbuf + ((size_t)(b * 8 + h) * 32 + c) * 1024;
#pragma unroll
        for (int n = 0; n < 16; n++) hs[n] = Si[n * 64 + p];
    }
    float dsk = sp[SP_DSK + layer * 8 + h];
    __syncthreads();  // bc_s ready; all conv reads of zraw done (x-raw now dead)

    // ---- final scan, y (bf16-rounded) -> y_s[32][YST] (zraw reuse) ----
    ushort_t* y_s = zraw;
#pragma unroll
    for (int tt = 0; tt < CHUNK; tt++) {
        float dAv = da_s[h * 32 + tt], dtv = dt_s[h * 32 + tt];
        float dtx = xs[tt] * dtv;
        float acc = 0.f;
        const float4* bcp = (const float4*)&bc_s[tt * 32];
#pragma unroll
        for (int j = 0; j < 8; j++) {
            float4 v = bcp[j];
            hs[2 * j] = hs[2 * j] * dAv + dtx * v.x;
            acc += hs[2 * j] * v.y;
            hs[2 * j + 1] = hs[2 * j + 1] * dAv + dtx * v.z;
            acc += hs[2 * j + 1] * v.w;
        }
        y_s[tt * YST + tid] = f2bfs(acc + xs[tt] * dsk);
    }
    __syncthreads();

    // ---- gating + RMSNorm in place; wave h handles rows h*4..h*4+3 ----
    {
        int lane = p;
        float4 rw0 = *(const float4*)(sp + SP_RMSW + layer * 512 + lane * 8);
        float4 rw1 = *(const float4*)(sp + SP_RMSW + layer * 512 + lane * 8 + 4);
        float rwv[8] = {rw0.x, rw0.y, rw0.z, rw0.w, rw1.x, rw1.y, rw1.z, rw1.w};
#pragma unroll
        for (int r = 0; r < 4; r++) {
            int tt = h * 4 + r;
            u8v yv = *(const u8v*)&y_s[tt * YST + lane * 8];
            u8v zv = *(const u8v*)(zxB + (size_t)(t0 + tt) * 1064 + lane * 8);
            float t[8];
            float ss = 0.f;
#pragma unroll
            for (int j2 = 0; j2 < 8; j2++) {
                float z = us2f(zv[j2]);
                float yy = us2f(yv[j2]);
                float tv = yy * (z * sigmoidf_(z));
                t[j2] = tv;
                ss += tv * tv;
            }
#pragma unroll
            for (int d = 32; d; d >>= 1) ss += __shfl_xor(ss, d, 64);
            float scale = rsqrtf(ss * (1.f / 512.f) + 1e-5f);
            u8v o;
#pragma unroll
            for (int j2 = 0; j2 < 8; j2++) o[j2] = f2bfs(t[j2] * scale * rwv[j2]);
            *(u8v*)&y_s[tt * YST + lane * 8] = o;
        }
    }
    __syncthreads();

    // ---- out_proj GEMM: C[32][256] = y_s[32][512] @ Wt[n][k]^T; wave h -> cols h*32.. ----
    int lm = p & 15, quad = p >> 4;
    f4v acc2[2][2];
#pragma unroll
    for (int mi = 0; mi < 2; mi++)
#pragma unroll
        for (int ni = 0; ni < 2; ni++) acc2[mi][ni] = (f4v){0.f, 0.f, 0.f, 0.f};
#pragma unroll
    for (int kk = 0; kk < 16; kk++) {
        s8v af[2], bw[2];
#pragma unroll
        for (int mi = 0; mi < 2; mi++)
            af[mi] = *(const s8v*)&y_s[(mi * 16 + lm) * YST + kk * 32 + quad * 8];
#pragma unroll
        for (int ni = 0; ni < 2; ni++)
            bw[ni] = *(const s8v*)(Wt + (size_t)(h * 32 + ni * 16 + lm) * 512 + kk * 32 + quad * 8);
#pragma unroll
        for (int mi = 0; mi < 2; mi++)
#pragma unroll
            for (int ni = 0; ni < 2; ni++)
                acc2[mi][ni] = __builtin_amdgcn_mfma_f32_16x16x32_bf16(af[mi], bw[ni], acc2[mi][ni], 0, 0, 0);
    }
    __syncthreads();  // all y_s reads complete before C_lds overwrite

    float* C_lds = (float*)zraw;  // [32][260]
#pragma unroll
    for (int mi = 0; mi < 2; mi++)
#pragma unroll
        for (int ni = 0; ni < 2; ni++)
#pragma unroll
            for (int rr = 0; rr < 4; rr++)
                C_lds[(mi * 16 + quad * 4 + rr) * 260 + h * 32 + ni * 16 + lm] = acc2[mi][ni][rr];
    __syncthreads();

    // ---- residual + LayerNorm; wave h rows h*4..h*4+3 ----
#pragma unroll
    for (int r = 0; r < 4; r++) {
        int tt = h * 4 + r;
        size_t off = (size_t)(b * 1024 + t0 + tt) * 256 + p * 4;
        float4 v = *(const float4*)(tok + off);
        float4 cv = *(const float4*)&C_lds[tt * 260 + p * 4];
        v.x += cv.x;
        v.y += cv.y;
        v.z += cv.z;
        v.w += cv.w;
        float s = v.x + v.y + v.z + v.w;
#pragma unroll
        for (int d = 32; d; d >>= 1) s += __shfl_xor(s, d, 64);
        float mean = s * (1.f / 256.f);
        float dx = v.x - mean, dy = v.y - mean, dz = v.z - mean, dw = v.w - mean;
        float ss = dx * dx + dy * dy + dz * dz + dw * dw;
#pragma unroll
        for (int d = 32; d; d >>= 1) ss += __shfl_xor(ss, d, 64);
        float inv = rsqrtf(ss * (1.f / 256.f) + 1e-5f);
        const float* lg = sp + SP_LNG + layer * 256 + p * 4;
        const float* lb = sp + SP_LNB + layer * 256 + p * 4;
        float r0 = dx * inv * lg[0] + lb[0];
        float r1 = dy * inv * lg[1] + lb[1];
        float r2 = dz * inv * lg[2] + lb[2];
        float r3 = dw * inv * lg[3] + lb[3];
        float4 rv;
        rv.x = r0; rv.y = r1; rv.z = r2; rv.w = r3;
        *(float4*)(tok + off) = rv;
        u4v ob;
        ob[0] = f2bfs(r0); ob[1] = f2bfs(r1); ob[2] = f2bfs(r2); ob[3] = f2bfs(r3);
        *(u4v*)(tokb + off) = ob;
    }
}

// ---------------- block reduction helper (head only) ----------------
DEV float block_sum256(float v, float* s4) {
#pragma unroll
    for (int off = 32; off; off >>= 1) v += __shfl_down(v, off, 64);
    __syncthreads();
    if ((threadIdx.x & 63) == 0) s4[threadIdx.x >> 6] = v;
    __syncthreads();
    return s4[0] + s4[1] + s4[2] + s4[3];
}

// ---------------- mean pool stage 1 ----------------
__global__ void k_pool1(const float* __restrict__ tok, float* __restrict__ ppart) {
    int b = blockIdx.x >> 4, chunk = blockIdx.x & 15;
    int c = threadIdx.x;
    float s = 0.f;
    for (int t = 0; t < 64; t++) s += tok[((size_t)b * 1024 + chunk * 64 + t) * 256 + c];
    ppart[(size_t)blockIdx.x * 256 + c] = s;
}

// ---------------- head (pool stage 2 fused) ----------------
__global__ __launch_bounds__(256) void k_head(const float* __restrict__ ppart, const float* __restrict__ sp,
                                              void* __restrict__ out, const void* __restrict__ g1) {
    __shared__ float s4[4];
    __shared__ float lds[256];
    int md = mode_of(g1);
    int b = blockIdx.x;
    int c = threadIdx.x;
    float v = 0.f;
#pragma unroll
    for (int k = 0; k < 16; k++) v += ppart[(size_t)(b * 16 + k) * 256 + c];
    v *= (1.f / 1024.f);
    float mean = block_sum256(v, s4) * (1.f / 256.f);
    float d = v - mean;
    float var = block_sum256(d * d, s4) * (1.f / 256.f);
    lds[c] = d * rsqrtf(var + 1e-5f) * sp[SP_HLG + c] + sp[SP_HLB + c];
    __syncthreads();
    if (c < 10) {
        float s = sp[SP_HB + c];
        for (int k = 0; k < 256; k++) s += lds[k] * sp[SP_HW + k * 10 + c];
        if (md)
            ((bf16*)out)[b * 10 + c] = f2bf(s);
        else
            ((float*)out)[b * 10 + c] = s;
    }
}

extern "C" void kernel_launch(void* const* d_in, const int* in_sizes, int n_in, void* d_out, int out_size,
                              void* d_ws, size_t ws_size, hipStream_t stream) {
    const void* x         = d_in[0];
    const void* stem_w1   = d_in[1];
    const void* stem_g1   = d_in[2];
    const void* stem_b1   = d_in[3];
    const void* stem_w2   = d_in[4];
    const void* stem_g2   = d_in[5];
    const void* stem_b2   = d_in[6];
    const void* in_w      = d_in[7];
    const void* conv_w    = d_in[8];
    const void* conv_b    = d_in[9];
    const void* dt_bias   = d_in[10];
    const void* A_log     = d_in[11];
    const void* D_skip    = d_in[12];
    const void* rms_w     = d_in[13];
    const void* out_w     = d_in[14];
    const void* ln_g      = d_in[15];
    const void* ln_b      = d_in[16];
    const void* head_ln_g = d_in[17];
    const void* head_ln_b = d_in[18];
    const void* head_w    = d_in[19];
    const void* head_b    = d_in[20];

    // ---- workspace layout (float units), ~99 MB ----
    float* ws     = (float*)d_ws;
    float* tok    = ws;                        // 2,097,152 f
    float* mbuf   = ws + 2097152;              // 2,097,152 f (Sbuf scan scratch)
    float* Hbuf   = ws + 4194304;              // 2,097,152 f
    float* parts  = ws + 6291456;              // 8,388,608 f (split-K partials, stem only)
    float* ppart  = ws + 14682112;             // 32,768 f
    float* Pbuf   = ws + 14714880;             // 2,048 f
    float* sp     = ws + 14716944;             // 18,944 f
    ushort_t* tokb = (ushort_t*)(ws + 14735888);  // 2,097,152 e
    ushort_t* wT  = (ushort_t*)(ws + 15784464);   // 2,142,208 e
    ushort_t* w1T   = wT;
    ushort_t* w2T   = wT + 4096;
    ushort_t* inwT  = wT + 528384;
    ushort_t* outwT = wT + 1617920;
    bf16* arena   = (bf16*)(ws + 16855568);    // 17,367,040 e
    bf16* zx      = arena;                     // 8,716,288 e
    ushort_t* patch = (ushort_t*)arena;        // 16,777,216 e (dead before zx)
    float* Sbuf    = mbuf;                     // scan scratch

    k_prep<<<(SP_TOTAL + 2142208 + 255) / 256, 256, 0, stream>>>(
        conv_w, conv_b, dt_bias, A_log, D_skip, rms_w, ln_g, ln_b, head_ln_g, head_ln_b, head_w, head_b,
        stem_g1, stem_b1, stem_g2, stem_b2, stem_w1, stem_w2, in_w, out_w, sp, wT);

    // stem: conv1 (inline im2col, patch-layout out), conv2 split-K 2, reduce(+BN+GELU)
    k_gemmT<2, 1, 32, 1><<<dim3(1, 2048, 1), 256, 0, stream>>>(
        (const ushort_t*)x, w1T, patch, 131072, 128, 32, 32, sp + SP_G1, sp + SP_B1, x, stem_g1);
    k_gemmT<0, 0, 64, 0><<<dim3(2, 128, 2), 256, 0, stream>>>(
        patch, w2T, parts, 8192, 256, 2048, 1024, nullptr, nullptr, nullptr, nullptr);
    k_stemred<<<2048, 256, 0, stream>>>(parts, sp, tok, tokb);

    for (int l = 0; l < 4; l++) {
        k_gemmT<0, 1, 64, 0><<<dim3(9, 128, 1), 256, 0, stream>>>(
            tokb, inwT + (size_t)l * 272384, zx, 8192, 1064, 256, 256, nullptr, nullptr, nullptr, nullptr);
        k_scan1<<<256, 512, 0, stream>>>(zx, sp, Sbuf, Pbuf, l);
        k_scan2<<<256, 256, 0, stream>>>(Sbuf, Pbuf, Hbuf);
        k_scan3go<<<256, 512, 0, stream>>>(zx, Hbuf, sp, outwT + (size_t)l * 131072, tok, tokb, l);
    }

    k_pool1<<<128, 256, 0, stream>>>(tok, ppart);
    k_head<<<8, 256, 0, stream>>>(ppart, sp, d_out, stem_g1);
}